// Round 2
// baseline (3303.498 us; speedup 1.0000x reference)
//
#include <hip/hip_runtime.h>
#include <hip/hip_bf16.h>
#include <math.h>

// Problem constants (B,S,D) = (4,4096,1024)
#define BDIM 4
#define SDIM 4096
#define DDIM 1024
#define MROWS (BDIM*SDIM)      // 16384
#define EPS 1e-6f
#define NCHUNK 64              // chunks along S
#define LCHUNK 64              // chunk length (NCHUNK*LCHUNK == SDIM)

typedef __hip_bfloat16 bf16;

// ---------------------------------------------------------------------------
// Guard-fail fill: encodes ws_size (MB) into d_out so a too-small workspace
// shows up as a clean absmax failure (= MB count) instead of a crash.
// ---------------------------------------------------------------------------
__global__ __launch_bounds__(256) void fill_kernel(float* __restrict__ out,
                                                   int n, float val)
{
    const int i = blockIdx.x * 256 + threadIdx.x;
    if (i < n) out[i] = val;
}

// ---------------------------------------------------------------------------
// RMSNorm: one block (256 threads) per row of D=1024. float4 per thread.
// ---------------------------------------------------------------------------
__global__ __launch_bounds__(256) void rmsnorm_kernel(
    const float* __restrict__ x, const float* __restrict__ scale,
    float* __restrict__ xn)
{
    const int row = blockIdx.x;
    const int tid = threadIdx.x;
    const float4* xr = reinterpret_cast<const float4*>(x + (size_t)row * DDIM);
    float4 v = xr[tid];
    float ss = v.x*v.x + v.y*v.y + v.z*v.z + v.w*v.w;
    #pragma unroll
    for (int off = 32; off > 0; off >>= 1)
        ss += __shfl_down(ss, off, 64);
    __shared__ float red[4];
    if ((tid & 63) == 0) red[tid >> 6] = ss;
    __syncthreads();
    ss = red[0] + red[1] + red[2] + red[3];
    const float inv = rsqrtf(ss * (1.0f / DDIM) + EPS);
    const float4 sc = reinterpret_cast<const float4*>(scale)[tid];
    float4 o;
    o.x = v.x * inv * sc.x;
    o.y = v.y * inv * sc.y;
    o.z = v.z * inv * sc.z;
    o.w = v.w * inv * sc.w;
    reinterpret_cast<float4*>(xn + (size_t)row * DDIM)[tid] = o;
}

// ---------------------------------------------------------------------------
// fp32 SGEMM: C[M,N] (+epilogue) = A[M,K] @ B[K,N]. 64x64 tile, BK=16,
// 4x4 microtile, 256 threads/block.
// MODE 0: C(f32)  = A@B
// MODE 1: C(bf16) = bf16(A@B)                       (k staging)
// MODE 2: C(bf16) = bf16(C * (A@B))                 (kv = k*v)
// MODE 3: C(f32)  = C * silu(A@B)                   (qg = q*silu(g))
// ---------------------------------------------------------------------------
#define BM 64
#define BN 64
#define BK 16

template <int MODE>
__global__ __launch_bounds__(256) void sgemm_kernel(
    const float* __restrict__ A, const float* __restrict__ Bw,
    void* __restrict__ Cv, int M, int N, int K)
{
    __shared__ __align__(16) float As[BK][BM + 4];  // As[k][m]
    __shared__ __align__(16) float Bs[BK][BN + 4];  // Bs[k][n]

    const int tid = threadIdx.x;
    const int tx = tid & 15;
    const int ty = tid >> 4;
    const int bm = blockIdx.y * BM;
    const int bn = blockIdx.x * BN;

    const int ar = tid >> 2;          // A row within tile (0..63)
    const int ac = (tid & 3) << 2;    // A k-offset (0,4,8,12)
    const int br = tid >> 4;          // B k-row (0..15)
    const int bc = (tid & 15) << 2;   // B col offset (0..60)

    const float* Aptr = A + (size_t)(bm + ar) * K + ac;
    const float* Bptr = Bw + (size_t)br * N + bn + bc;

    float acc[4][4] = {};

    for (int kt = 0; kt < K; kt += BK) {
        const float4 av = *reinterpret_cast<const float4*>(Aptr + kt);
        const float4 bv = *reinterpret_cast<const float4*>(Bptr + (size_t)kt * N);
        __syncthreads();
        As[ac + 0][ar] = av.x;
        As[ac + 1][ar] = av.y;
        As[ac + 2][ar] = av.z;
        As[ac + 3][ar] = av.w;
        *reinterpret_cast<float4*>(&Bs[br][bc]) = bv;
        __syncthreads();
        #pragma unroll
        for (int kk = 0; kk < BK; ++kk) {
            const float4 ta = *reinterpret_cast<const float4*>(&As[kk][ty << 2]);
            const float4 tb = *reinterpret_cast<const float4*>(&Bs[kk][tx << 2]);
            const float areg[4] = {ta.x, ta.y, ta.z, ta.w};
            const float breg[4] = {tb.x, tb.y, tb.z, tb.w};
            #pragma unroll
            for (int i = 0; i < 4; ++i)
                #pragma unroll
                for (int j = 0; j < 4; ++j)
                    acc[i][j] = fmaf(areg[i], breg[j], acc[i][j]);
        }
    }

    #pragma unroll
    for (int i = 0; i < 4; ++i) {
        const size_t r = (size_t)(bm + (ty << 2) + i) * N + bn + (tx << 2);
        if (MODE == 0) {
            float4 o = make_float4(acc[i][0], acc[i][1], acc[i][2], acc[i][3]);
            *reinterpret_cast<float4*>(&((float*)Cv)[r]) = o;
        } else if (MODE == 1) {
            bf16* C = (bf16*)Cv;
            #pragma unroll
            for (int j = 0; j < 4; ++j)
                C[r + j] = __float2bfloat16(acc[i][j]);
        } else if (MODE == 2) {
            bf16* C = (bf16*)Cv;
            #pragma unroll
            for (int j = 0; j < 4; ++j) {
                const float kvf = __bfloat162float(C[r + j]) * acc[i][j];
                C[r + j] = __float2bfloat16(kvf);
            }
        } else {
            float* C = (float*)Cv;
            #pragma unroll
            for (int j = 0; j < 4; ++j) {
                const float gv = acc[i][j];
                const float silu = gv / (1.0f + expf(-gv));
                C[r + j] = C[r + j] * silu;
            }
        }
    }
}

// ---------------------------------------------------------------------------
// a-transform (in-place, fp32): a_c = sigmoid(|a|) * exp(i*angle(a))
//  a layout: [M, 2D]; real at [m, d], imag at [m, D+d]
// ---------------------------------------------------------------------------
__global__ __launch_bounds__(256) void atrans_kernel(float* __restrict__ a)
{
    const int i = blockIdx.x * 256 + threadIdx.x;   // 0 .. M*D-1
    const int m = i >> 10;
    const int d = i & 1023;
    const size_t i0 = (size_t)m * (2 * DDIM) + d;
    const float ar = a[i0];
    const float ai = a[i0 + DDIM];
    const float r = sqrtf(ar * ar + ai * ai);
    const float mag = 1.0f / (1.0f + expf(-r));
    if (r > 0.0f) {
        const float s = mag / r;
        a[i0] = ar * s;
        a[i0 + DDIM] = ai * s;
    } else {
        a[i0] = 0.5f;
        a[i0 + DDIM] = 0.0f;
    }
}

// ---------------------------------------------------------------------------
// Scan phase 1: per-(b,chunk,d) local scan; emit (A_prod, H_local) float4.
// h_t = a_t*h_{t-1} + kv_t  (complex a, real kv), h init 0, A init 1.
// ---------------------------------------------------------------------------
__global__ __launch_bounds__(256) void scan1_kernel(
    const float* __restrict__ a, const bf16* __restrict__ kvb,
    float4* __restrict__ state)
{
    const int t = blockIdx.x * 256 + threadIdx.x;   // B*NCHUNK*D
    const int d = t & 1023;
    const int c = (t >> 10) & (NCHUNK - 1);
    const int b = t >> 16;
    size_t base  = ((size_t)(b * SDIM + c * LCHUNK)) * DDIM + d;
    size_t abase = ((size_t)(b * SDIM + c * LCHUNK)) * (2 * DDIM) + d;
    float Ar = 1.0f, Ai = 0.0f, Hr = 0.0f, Hi = 0.0f;
    for (int s = 0; s < LCHUNK; ++s) {
        const float arr = a[abase];
        const float aii = a[abase + DDIM];
        const float kv = __bfloat162float(kvb[base]);
        const float hr = arr * Hr - aii * Hi + kv;
        const float hi = arr * Hi + aii * Hr;
        Hr = hr; Hi = hi;
        const float nr = arr * Ar - aii * Ai;
        const float ni = arr * Ai + aii * Ar;
        Ar = nr; Ai = ni;
        base += DDIM;
        abase += 2 * DDIM;
    }
    state[t] = make_float4(Ar, Ai, Hr, Hi);
}

// ---------------------------------------------------------------------------
// Scan phase 2: combine chunk states sequentially per channel; write carry-in
// (exclusive prefix) per chunk.
// ---------------------------------------------------------------------------
__global__ __launch_bounds__(256) void scan2_kernel(
    const float4* __restrict__ state, float2* __restrict__ carry)
{
    const int t = blockIdx.x * 256 + threadIdx.x;  // B*D = 4096
    const int d = t & 1023;
    const int b = t >> 10;
    float cr = 0.0f, ci = 0.0f;
    for (int c = 0; c < NCHUNK; ++c) {
        const size_t idx = ((size_t)(b * NCHUNK + c)) * DDIM + d;
        carry[idx] = make_float2(cr, ci);
        const float4 st = state[idx];
        const float nr = st.x * cr - st.y * ci + st.z;
        const float ni = st.x * ci + st.y * cr + st.w;
        cr = nr; ci = ni;
    }
}

// ---------------------------------------------------------------------------
// Scan phase 3: re-run local scan with carry-in; y = qg * Re(h).
// ---------------------------------------------------------------------------
__global__ __launch_bounds__(256) void scan3_kernel(
    const float* __restrict__ a, const bf16* __restrict__ kvb,
    const float* __restrict__ qg, const float2* __restrict__ carry,
    float* __restrict__ y)
{
    const int t = blockIdx.x * 256 + threadIdx.x;   // B*NCHUNK*D
    const int d = t & 1023;
    const int c = (t >> 10) & (NCHUNK - 1);
    const int b = t >> 16;
    size_t base  = ((size_t)(b * SDIM + c * LCHUNK)) * DDIM + d;
    size_t abase = ((size_t)(b * SDIM + c * LCHUNK)) * (2 * DDIM) + d;
    const float2 h0 = carry[t];
    float Hr = h0.x, Hi = h0.y;
    for (int s = 0; s < LCHUNK; ++s) {
        const float arr = a[abase];
        const float aii = a[abase + DDIM];
        const float kv = __bfloat162float(kvb[base]);
        const float hr = arr * Hr - aii * Hi + kv;
        const float hi = arr * Hi + aii * Hr;
        Hr = hr; Hi = hi;
        y[base] = qg[base] * Hr;
        base += DDIM;
        abase += 2 * DDIM;
    }
}

// ---------------------------------------------------------------------------
// kernel_launch
//
// Workspace layout (ws budget = 226 MB):
//   W0: [SZ f32]   xn, later y; scan `state` (4 MB) overlaps W0 after xn dies
//   W1: [SZ bf16]  k staged bf16, then kv = bf16(k*v)
//   W2: [2*SZ f32] a (real | imag halves per row)
//   carry: [B*NCHUNK*D float2] = 2 MB
// qg = q*silu(g) lives in d_out until the final GEMM overwrites it.
// ---------------------------------------------------------------------------
extern "C" void kernel_launch(void* const* d_in, const int* in_sizes, int n_in,
                              void* d_out, int out_size, void* d_ws, size_t ws_size,
                              hipStream_t stream)
{
    const float* x        = (const float*)d_in[0];
    const float* wq       = (const float*)d_in[1];
    const float* wk       = (const float*)d_in[2];
    const float* wv       = (const float*)d_in[3];
    const float* wa       = (const float*)d_in[4];
    const float* wg       = (const float*)d_in[5];
    const float* wo       = (const float*)d_in[6];
    const float* rms_scale= (const float*)d_in[7];
    float* out = (float*)d_out;

    const size_t SZ = (size_t)MROWS * DDIM;   // 16,777,216 elements
    char* ws = (char*)d_ws;
    float* W0      = (float*)ws;                            // SZ f32
    bf16*  W1      = (bf16*) (ws + SZ * 4);                 // SZ bf16
    float* W2      = (float*)(ws + SZ * 4 + SZ * 2);        // 2*SZ f32
    float2* carry  = (float2*)(ws + SZ * 4 + SZ * 2 + SZ * 8);
    float4* state  = (float4*)W0;                           // overlaps dead xn

    const size_t needed = SZ * 4 + SZ * 2 + SZ * 8
                        + (size_t)BDIM * NCHUNK * DDIM * sizeof(float2);
    if (ws_size < needed) {
        // diagnostic: encode ws_size in MB as the output value
        const float marker = (float)(ws_size >> 20);
        fill_kernel<<<(out_size + 255) / 256, 256, 0, stream>>>(out, out_size, marker);
        return;
    }

    // 1. RMSNorm
    rmsnorm_kernel<<<MROWS, 256, 0, stream>>>(x, rms_scale, W0);

    // 2. Projections (+fused epilogues)
    dim3 blk(256);
    dim3 grid1(DDIM / BN, MROWS / BM);       // N=1024
    dim3 grid2(2 * DDIM / BN, MROWS / BM);   // N=2048
    sgemm_kernel<0><<<grid1, blk, 0, stream>>>(W0, wq, out, MROWS, DDIM, DDIM);  // q
    sgemm_kernel<3><<<grid1, blk, 0, stream>>>(W0, wg, out, MROWS, DDIM, DDIM);  // qg = q*silu(g)
    sgemm_kernel<1><<<grid1, blk, 0, stream>>>(W0, wk, W1,  MROWS, DDIM, DDIM);  // k (bf16)
    sgemm_kernel<2><<<grid1, blk, 0, stream>>>(W0, wv, W1,  MROWS, DDIM, DDIM);  // kv = k*v (bf16)
    sgemm_kernel<0><<<grid2, blk, 0, stream>>>(W0, wa, W2,  MROWS, 2 * DDIM, DDIM); // a

    // 3. a -> sigmoid(|a|)*exp(i*angle(a)), in place
    atrans_kernel<<<(MROWS * DDIM) / 256, 256, 0, stream>>>(W2);

    // 4. chunked complex scan (state overlaps dead xn in W0)
    const int nscan = BDIM * NCHUNK * DDIM;   // 262144
    scan1_kernel<<<nscan / 256, 256, 0, stream>>>(W2, W1, state);
    scan2_kernel<<<(BDIM * DDIM) / 256, 256, 0, stream>>>(state, carry);
    scan3_kernel<<<nscan / 256, 256, 0, stream>>>(W2, W1, out, carry, W0);

    // 5. out = y @ wo  (overwrites dead qg)
    sgemm_kernel<0><<<grid1, blk, 0, stream>>>(W0, wo, out, MROWS, DDIM, DDIM);
}

// Round 4
// 654.732 us; speedup vs baseline: 5.0456x; 5.0456x over previous
//
#include <hip/hip_runtime.h>
#include <hip/hip_bf16.h>
#include <math.h>

// Problem constants (B,S,D) = (4,4096,1024)
#define BDIM 4
#define SDIM 4096
#define DDIM 1024
#define MROWS (BDIM*SDIM)      // 16384
#define EPS 1e-6f
#define NCHUNK 64              // chunks along S
#define LCHUNK 64              // chunk length (NCHUNK*LCHUNK == SDIM)

typedef _Float16 f16_t;
typedef _Float16 f16x4_t __attribute__((ext_vector_type(4)));
typedef _Float16 f16x8_t __attribute__((ext_vector_type(8)));     // MFMA A/B frag (4 VGPRs)
typedef float    f32x4_t __attribute__((ext_vector_type(4)));     // MFMA C/D frag

// async global->LDS, 16B per lane (dest = wave-uniform base + lane*16)
__device__ __forceinline__ void gload16(const void* g, void* l) {
    __builtin_amdgcn_global_load_lds(
        (const __attribute__((address_space(1))) unsigned int*)g,
        (__attribute__((address_space(3))) unsigned int*)l, 16, 0, 0);
}

// ---------------------------------------------------------------------------
// Guard-fail fill (encodes ws_size MB as output on too-small workspace)
// ---------------------------------------------------------------------------
__global__ __launch_bounds__(256) void fill_kernel(float* __restrict__ out,
                                                   int n, float val)
{
    const int i = blockIdx.x * 256 + threadIdx.x;
    if (i < n) out[i] = val;
}

// ---------------------------------------------------------------------------
// RMSNorm: one block per row of D=1024; outputs fp16 xn.
// ---------------------------------------------------------------------------
__global__ __launch_bounds__(256) void rmsnorm_kernel(
    const float* __restrict__ x, const float* __restrict__ scale,
    f16_t* __restrict__ xn)
{
    const int row = blockIdx.x;
    const int tid = threadIdx.x;
    const float4 v = reinterpret_cast<const float4*>(x + (size_t)row * DDIM)[tid];
    float ss = v.x*v.x + v.y*v.y + v.z*v.z + v.w*v.w;
    #pragma unroll
    for (int off = 32; off > 0; off >>= 1)
        ss += __shfl_down(ss, off, 64);
    __shared__ float red[4];
    if ((tid & 63) == 0) red[tid >> 6] = ss;
    __syncthreads();
    ss = red[0] + red[1] + red[2] + red[3];
    const float inv = rsqrtf(ss * (1.0f / DDIM) + EPS);
    const float4 sc = reinterpret_cast<const float4*>(scale)[tid];
    f16x4_t o;
    o.x = (f16_t)(v.x * inv * sc.x);
    o.y = (f16_t)(v.y * inv * sc.y);
    o.z = (f16_t)(v.z * inv * sc.z);
    o.w = (f16_t)(v.w * inv * sc.w);
    reinterpret_cast<f16x4_t*>(xn + (size_t)row * DDIM)[tid] = o;
}

// ---------------------------------------------------------------------------
// Weight prep: W[K][N] f32 -> WT[N][K] fp16 (32x32 LDS tile transpose)
// ---------------------------------------------------------------------------
__global__ __launch_bounds__(256) void transpose_f16_kernel(
    const float* __restrict__ W, f16_t* __restrict__ WT, int K, int N)
{
    __shared__ float t[32][33];
    const int kb = blockIdx.y * 32;
    const int nb = blockIdx.x * 32;
    const int r  = threadIdx.x >> 3;          // 0..31
    const int c0 = (threadIdx.x & 7) << 2;    // 0,4,...,28
    const float4 v = *reinterpret_cast<const float4*>(&W[(size_t)(kb + r) * N + nb + c0]);
    t[r][c0 + 0] = v.x; t[r][c0 + 1] = v.y; t[r][c0 + 2] = v.z; t[r][c0 + 3] = v.w;
    __syncthreads();
    f16x4_t o;
    o.x = (f16_t)t[c0 + 0][r];
    o.y = (f16_t)t[c0 + 1][r];
    o.z = (f16_t)t[c0 + 2][r];
    o.w = (f16_t)t[c0 + 3][r];
    *reinterpret_cast<f16x4_t*>(&WT[(size_t)(nb + r) * K + kb + c0]) = o;
}

// ---------------------------------------------------------------------------
// fp16 MFMA GEMM (m97 pattern): C[M,N] = A[M,K] @ BT[N,K]^T
// 128x128 tile, BK=32, 256 threads = 4 waves, each wave 64x64 (4x4 MFMA tiles).
// MODE 0: C(f32)  = A@B
// MODE 1: C(f16)  = f16(A@B)                   (k staging)
// MODE 2: C(f16)  = f16(C * (A@B))             (kv = k*v)
// MODE 3: C(f32)  = C * silu(A@B)              (qg = q*silu(g))
// ---------------------------------------------------------------------------
template <int MODE>
__global__ __launch_bounds__(256, 2) void mfma_gemm_kernel(
    const f16_t* __restrict__ A, const f16_t* __restrict__ BT,
    void* __restrict__ Cv, int M, int N, int K)
{
    __shared__ __align__(16) f16_t As[128 * 32];   // [m][k], 64B rows
    __shared__ __align__(16) f16_t Bs[128 * 32];   // [n][k]

    const int tid  = threadIdx.x;
    const int wave = tid >> 6;
    const int lane = tid & 63;
    const int bm = blockIdx.y * 128;
    const int bn = blockIdx.x * 128;
    const int wm = (wave & 1) * 64;
    const int wn = (wave >> 1) * 64;

    // staging maps: thread t loads rows (t>>2) and (t>>2)+64, 16B chunk (t&3)
    const int sr = tid >> 2;
    const int sc = (tid & 3) * 8;   // f16 element offset within row
    const f16_t* Ag = A  + (size_t)(bm + sr) * K + sc;
    const f16_t* Bg = BT + (size_t)(bn + sr) * K + sc;
    f16_t* Al0 = As + tid * 8;             // == (sr*32 + sc)
    f16_t* Al1 = As + 64 * 32 + tid * 8;
    f16_t* Bl0 = Bs + tid * 8;
    f16_t* Bl1 = Bs + 64 * 32 + tid * 8;
    const size_t rowskip = (size_t)64 * K;

    f32x4_t acc[4][4] = {};

    const int fm = lane & 15;
    const int kh = (lane >> 4) << 3;   // 0,8,16,24

    for (int kt = 0; kt < K; kt += 32) {
        gload16(Ag + kt, Al0);
        gload16(Ag + rowskip + kt, Al1);
        gload16(Bg + kt, Bl0);
        gload16(Bg + rowskip + kt, Bl1);
        __syncthreads();   // drains vmcnt -> tiles visible in LDS

        f16x8_t af[4], bfr[4];
        #pragma unroll
        for (int i = 0; i < 4; ++i)
            af[i] = *reinterpret_cast<const f16x8_t*>(&As[(wm + i * 16 + fm) * 32 + kh]);
        #pragma unroll
        for (int j = 0; j < 4; ++j)
            bfr[j] = *reinterpret_cast<const f16x8_t*>(&Bs[(wn + j * 16 + fm) * 32 + kh]);
        #pragma unroll
        for (int i = 0; i < 4; ++i)
            #pragma unroll
            for (int j = 0; j < 4; ++j)
                acc[i][j] = __builtin_amdgcn_mfma_f32_16x16x32_f16(
                    af[i], bfr[j], acc[i][j], 0, 0, 0);
        __syncthreads();   // all waves done reading before next overwrite
    }

    // epilogue: D row=(lane>>4)*4+reg, col=lane&15  (m89/m91-verified)
    const int erow = (lane >> 4) << 2;
    const int ecol = lane & 15;
    #pragma unroll
    for (int i = 0; i < 4; ++i) {
        #pragma unroll
        for (int j = 0; j < 4; ++j) {
            const int row0 = bm + wm + i * 16 + erow;
            const int col  = bn + wn + j * 16 + ecol;
            #pragma unroll
            for (int rg = 0; rg < 4; ++rg) {
                const size_t idx = (size_t)(row0 + rg) * N + col;
                const float val = acc[i][j][rg];
                if (MODE == 0) {
                    ((float*)Cv)[idx] = val;
                } else if (MODE == 1) {
                    ((f16_t*)Cv)[idx] = (f16_t)val;
                } else if (MODE == 2) {
                    f16_t* C = (f16_t*)Cv;
                    C[idx] = (f16_t)((float)C[idx] * val);
                } else {
                    float* C = (float*)Cv;
                    const float s = val / (1.0f + expf(-val));
                    C[idx] = C[idx] * s;
                }
            }
        }
    }
}

// ---------------------------------------------------------------------------
// a-transform (in-place, fp32): a_c = sigmoid(|a|) * exp(i*angle(a))
// ---------------------------------------------------------------------------
__global__ __launch_bounds__(256) void atrans_kernel(float* __restrict__ a)
{
    const int i = blockIdx.x * 256 + threadIdx.x;   // 0 .. M*D-1
    const int m = i >> 10;
    const int d = i & 1023;
    const size_t i0 = (size_t)m * (2 * DDIM) + d;
    const float ar = a[i0];
    const float ai = a[i0 + DDIM];
    const float r = sqrtf(ar * ar + ai * ai);
    const float mag = 1.0f / (1.0f + expf(-r));
    if (r > 0.0f) {
        const float s = mag / r;
        a[i0] = ar * s;
        a[i0 + DDIM] = ai * s;
    } else {
        a[i0] = 0.5f;
        a[i0 + DDIM] = 0.0f;
    }
}

// ---------------------------------------------------------------------------
// Scan phase 1: per-(b,chunk,d) local scan; emit (A_prod, H_local) float4.
// h_t = a_t*h_{t-1} + kv_t  (complex a, real kv), h init 0, A init 1.
// ---------------------------------------------------------------------------
__global__ __launch_bounds__(256) void scan1_kernel(
    const float* __restrict__ a, const f16_t* __restrict__ kvb,
    float4* __restrict__ state)
{
    const int t = blockIdx.x * 256 + threadIdx.x;   // B*NCHUNK*D
    const int d = t & 1023;
    const int c = (t >> 10) & (NCHUNK - 1);
    const int b = t >> 16;
    size_t base  = ((size_t)(b * SDIM + c * LCHUNK)) * DDIM + d;
    size_t abase = ((size_t)(b * SDIM + c * LCHUNK)) * (2 * DDIM) + d;
    float Ar = 1.0f, Ai = 0.0f, Hr = 0.0f, Hi = 0.0f;
    for (int s = 0; s < LCHUNK; ++s) {
        const float arr = a[abase];
        const float aii = a[abase + DDIM];
        const float kv = (float)kvb[base];
        const float hr = arr * Hr - aii * Hi + kv;
        const float hi = arr * Hi + aii * Hr;
        Hr = hr; Hi = hi;
        const float nr = arr * Ar - aii * Ai;
        const float ni = arr * Ai + aii * Ar;
        Ar = nr; Ai = ni;
        base += DDIM;
        abase += 2 * DDIM;
    }
    state[t] = make_float4(Ar, Ai, Hr, Hi);
}

// ---------------------------------------------------------------------------
// Scan phase 2: sequential chunk-state combine per channel -> carry-in.
// ---------------------------------------------------------------------------
__global__ __launch_bounds__(256) void scan2_kernel(
    const float4* __restrict__ state, float2* __restrict__ carry)
{
    const int t = blockIdx.x * 256 + threadIdx.x;  // B*D = 4096
    const int d = t & 1023;
    const int b = t >> 10;
    float cr = 0.0f, ci = 0.0f;
    for (int c = 0; c < NCHUNK; ++c) {
        const size_t idx = ((size_t)(b * NCHUNK + c)) * DDIM + d;
        carry[idx] = make_float2(cr, ci);
        const float4 st = state[idx];
        const float nr = st.x * cr - st.y * ci + st.z;
        const float ni = st.x * ci + st.y * cr + st.w;
        cr = nr; ci = ni;
    }
}

// ---------------------------------------------------------------------------
// Scan phase 3: re-scan with carry; y(f16) = qg * Re(h).
// ---------------------------------------------------------------------------
__global__ __launch_bounds__(256) void scan3_kernel(
    const float* __restrict__ a, const f16_t* __restrict__ kvb,
    const float* __restrict__ qg, const float2* __restrict__ carry,
    f16_t* __restrict__ y)
{
    const int t = blockIdx.x * 256 + threadIdx.x;   // B*NCHUNK*D
    const int d = t & 1023;
    const int c = (t >> 10) & (NCHUNK - 1);
    const int b = t >> 16;
    size_t base  = ((size_t)(b * SDIM + c * LCHUNK)) * DDIM + d;
    size_t abase = ((size_t)(b * SDIM + c * LCHUNK)) * (2 * DDIM) + d;
    const float2 h0 = carry[t];
    float Hr = h0.x, Hi = h0.y;
    for (int s = 0; s < LCHUNK; ++s) {
        const float arr = a[abase];
        const float aii = a[abase + DDIM];
        const float kv = (float)kvb[base];
        const float hr = arr * Hr - aii * Hi + kv;
        const float hi = arr * Hi + aii * Hr;
        Hr = hr; Hi = hi;
        y[base] = (f16_t)(qg[base] * Hr);
        base += DDIM;
        abase += 2 * DDIM;
    }
}

// ---------------------------------------------------------------------------
// kernel_launch
//
// Workspace layout:
//   W0:   [SZ f16]   xn; later y (scan `state` f32x4 4MB overlaps, dead by scan3)
//   W1:   [SZ f16]   k staged, then kv = f16(k*v)
//   W2:   [2*SZ f32] a (real | imag halves per row)
//   WT:   [7M f16]   transposed weights: q,k,v,g,o (1M each) + a (2M)
//   carry:[B*NCHUNK*D float2] = 2 MB
// qg = q*silu(g) lives in d_out until the final GEMM overwrites it.
// ---------------------------------------------------------------------------
extern "C" void kernel_launch(void* const* d_in, const int* in_sizes, int n_in,
                              void* d_out, int out_size, void* d_ws, size_t ws_size,
                              hipStream_t stream)
{
    const float* x        = (const float*)d_in[0];
    const float* wq       = (const float*)d_in[1];
    const float* wk       = (const float*)d_in[2];
    const float* wv       = (const float*)d_in[3];
    const float* wa       = (const float*)d_in[4];
    const float* wg       = (const float*)d_in[5];
    const float* wo       = (const float*)d_in[6];
    const float* rms_scale= (const float*)d_in[7];
    float* out = (float*)d_out;

    const size_t SZ = (size_t)MROWS * DDIM;   // 16,777,216 elements
    char* ws = (char*)d_ws;
    f16_t* W0   = (f16_t*)ws;                          // SZ f16
    f16_t* W1   = (f16_t*)(ws + SZ * 2);               // SZ f16
    float* W2   = (float*)(ws + SZ * 4);               // 2*SZ f32
    f16_t* WT   = (f16_t*)(ws + SZ * 12);              // 7M f16
    const size_t WSZ = (size_t)DDIM * DDIM;            // 1,048,576
    f16_t* WTq = WT;
    f16_t* WTk = WT + WSZ;
    f16_t* WTv = WT + 2 * WSZ;
    f16_t* WTg = WT + 3 * WSZ;
    f16_t* WTo = WT + 4 * WSZ;
    f16_t* WTa = WT + 5 * WSZ;                         // 2M elements
    float2* carry = (float2*)(ws + SZ * 12 + 7 * WSZ * 2);  // 2 MB
    float4* state = (float4*)W0;                       // overlaps dead xn

    const size_t needed = SZ * 12 + 7 * WSZ * 2
                        + (size_t)BDIM * NCHUNK * DDIM * sizeof(float2);
    if (ws_size < needed) {
        const float marker = (float)(ws_size >> 20);
        fill_kernel<<<(out_size + 255) / 256, 256, 0, stream>>>(out, out_size, marker);
        return;
    }

    // 1. RMSNorm -> f16 xn
    rmsnorm_kernel<<<MROWS, 256, 0, stream>>>(x, rms_scale, W0);

    // 2. Weight prep: W[K][N] f32 -> WT[N][K] f16
    dim3 tblk(256);
    dim3 tg1(DDIM / 32, DDIM / 32);       // 1024x1024
    dim3 tg2(2 * DDIM / 32, DDIM / 32);   // 1024x2048
    transpose_f16_kernel<<<tg1, tblk, 0, stream>>>(wq, WTq, DDIM, DDIM);
    transpose_f16_kernel<<<tg1, tblk, 0, stream>>>(wk, WTk, DDIM, DDIM);
    transpose_f16_kernel<<<tg1, tblk, 0, stream>>>(wv, WTv, DDIM, DDIM);
    transpose_f16_kernel<<<tg1, tblk, 0, stream>>>(wg, WTg, DDIM, DDIM);
    transpose_f16_kernel<<<tg1, tblk, 0, stream>>>(wo, WTo, DDIM, DDIM);
    transpose_f16_kernel<<<tg2, tblk, 0, stream>>>(wa, WTa, DDIM, 2 * DDIM);

    // 3. Projections (+fused epilogues), MFMA fp16
    dim3 blk(256);
    dim3 g1(DDIM / 128, MROWS / 128);       // (8,128)
    dim3 g2(2 * DDIM / 128, MROWS / 128);   // (16,128)
    mfma_gemm_kernel<0><<<g1, blk, 0, stream>>>(W0, WTq, out, MROWS, DDIM, DDIM);      // q
    mfma_gemm_kernel<3><<<g1, blk, 0, stream>>>(W0, WTg, out, MROWS, DDIM, DDIM);      // qg
    mfma_gemm_kernel<1><<<g1, blk, 0, stream>>>(W0, WTk, W1,  MROWS, DDIM, DDIM);      // k
    mfma_gemm_kernel<2><<<g1, blk, 0, stream>>>(W0, WTv, W1,  MROWS, DDIM, DDIM);      // kv
    mfma_gemm_kernel<0><<<g2, blk, 0, stream>>>(W0, WTa, W2,  MROWS, 2 * DDIM, DDIM);  // a

    // 4. a -> sigmoid(|a|)*exp(i*angle(a)), in place
    atrans_kernel<<<(MROWS * DDIM) / 256, 256, 0, stream>>>(W2);

    // 5. chunked complex scan
    const int nscan = BDIM * NCHUNK * DDIM;   // 262144
    scan1_kernel<<<nscan / 256, 256, 0, stream>>>(W2, W1, state);
    scan2_kernel<<<(BDIM * DDIM) / 256, 256, 0, stream>>>(state, carry);
    scan3_kernel<<<nscan / 256, 256, 0, stream>>>(W2, W1, out, carry, W0);

    // 6. out = y @ wo
    mfma_gemm_kernel<0><<<g1, blk, 0, stream>>>(W0, WTo, out, MROWS, DDIM, DDIM);
}

// Round 5
// 591.256 us; speedup vs baseline: 5.5873x; 1.1074x over previous
//
#include <hip/hip_runtime.h>
#include <hip/hip_bf16.h>
#include <math.h>

// Problem constants (B,S,D) = (4,4096,1024)
#define BDIM 4
#define SDIM 4096
#define DDIM 1024
#define MROWS (BDIM*SDIM)      // 16384
#define EPS 1e-6f
#define NCHUNK 64              // chunks along S
#define LCHUNK 64              // chunk length (NCHUNK*LCHUNK == SDIM)

typedef _Float16 f16_t;
typedef _Float16 f16x4_t __attribute__((ext_vector_type(4)));
typedef _Float16 f16x8_t __attribute__((ext_vector_type(8)));     // MFMA A/B frag (4 VGPRs)
typedef float    f32x4_t __attribute__((ext_vector_type(4)));     // MFMA C/D frag

// async global->LDS, 16B per lane (dest = wave-uniform base + lane*16)
__device__ __forceinline__ void gload16(const void* g, void* l) {
    __builtin_amdgcn_global_load_lds(
        (const __attribute__((address_space(1))) unsigned int*)g,
        (__attribute__((address_space(3))) unsigned int*)l, 16, 0, 0);
}

// ---------------------------------------------------------------------------
// Guard-fail fill (encodes ws_size MB as output on too-small workspace)
// ---------------------------------------------------------------------------
__global__ __launch_bounds__(256) void fill_kernel(float* __restrict__ out,
                                                   int n, float val)
{
    const int i = blockIdx.x * 256 + threadIdx.x;
    if (i < n) out[i] = val;
}

// ---------------------------------------------------------------------------
// RMSNorm: one block per row of D=1024; outputs fp16 xn.
// ---------------------------------------------------------------------------
__global__ __launch_bounds__(256) void rmsnorm_kernel(
    const float* __restrict__ x, const float* __restrict__ scale,
    f16_t* __restrict__ xn)
{
    const int row = blockIdx.x;
    const int tid = threadIdx.x;
    const float4 v = reinterpret_cast<const float4*>(x + (size_t)row * DDIM)[tid];
    float ss = v.x*v.x + v.y*v.y + v.z*v.z + v.w*v.w;
    #pragma unroll
    for (int off = 32; off > 0; off >>= 1)
        ss += __shfl_down(ss, off, 64);
    __shared__ float red[4];
    if ((tid & 63) == 0) red[tid >> 6] = ss;
    __syncthreads();
    ss = red[0] + red[1] + red[2] + red[3];
    const float inv = rsqrtf(ss * (1.0f / DDIM) + EPS);
    const float4 sc = reinterpret_cast<const float4*>(scale)[tid];
    f16x4_t o;
    o.x = (f16_t)(v.x * inv * sc.x);
    o.y = (f16_t)(v.y * inv * sc.y);
    o.z = (f16_t)(v.z * inv * sc.z);
    o.w = (f16_t)(v.w * inv * sc.w);
    reinterpret_cast<f16x4_t*>(xn + (size_t)row * DDIM)[tid] = o;
}

// ---------------------------------------------------------------------------
// Weight prep: W[K][N] f32 -> WT[N][K] fp16 (32x32 LDS tile transpose)
// ---------------------------------------------------------------------------
__global__ __launch_bounds__(256) void transpose_f16_kernel(
    const float* __restrict__ W, f16_t* __restrict__ WT, int K, int N)
{
    __shared__ float t[32][33];
    const int kb = blockIdx.y * 32;
    const int nb = blockIdx.x * 32;
    const int r  = threadIdx.x >> 3;          // 0..31
    const int c0 = (threadIdx.x & 7) << 2;    // 0,4,...,28
    const float4 v = *reinterpret_cast<const float4*>(&W[(size_t)(kb + r) * N + nb + c0]);
    t[r][c0 + 0] = v.x; t[r][c0 + 1] = v.y; t[r][c0 + 2] = v.z; t[r][c0 + 3] = v.w;
    __syncthreads();
    f16x4_t o;
    o.x = (f16_t)t[c0 + 0][r];
    o.y = (f16_t)t[c0 + 1][r];
    o.z = (f16_t)t[c0 + 2][r];
    o.w = (f16_t)t[c0 + 3][r];
    *reinterpret_cast<f16x4_t*>(&WT[(size_t)(nb + r) * K + kb + c0]) = o;
}

// ---------------------------------------------------------------------------
// Weight prep for wa: W[K][2048] f32 -> WTa[n][K] f16 with INTERLEAVED rows:
// output row n corresponds to original column (n>>1) + (n&1)*1024, so the
// a-GEMM's N dimension holds (re,im) channel pairs in adjacent columns.
// ---------------------------------------------------------------------------
__global__ __launch_bounds__(256) void transpose_a_kernel(
    const float* __restrict__ W, f16_t* __restrict__ WT)
{
    const int K = DDIM, N = 2 * DDIM;
    __shared__ float t[32][33];
    const int kb = blockIdx.y * 32;
    const int nb = blockIdx.x * 32;   // output row block (interleaved space)
    const int r  = threadIdx.x >> 3;          // 0..31 (k row in tile)
    const int c0 = (threadIdx.x & 7) << 2;    // 0,4,...,28 (tile col)
    // tile cols 0..15 = real strip (orig cols nb/2 .. nb/2+15),
    // tile cols 16..31 = imag strip (orig cols 1024+nb/2 .. +15)
    const int base = (c0 < 16) ? ((nb >> 1) + c0) : (DDIM + (nb >> 1) + c0 - 16);
    const float4 v = *reinterpret_cast<const float4*>(&W[(size_t)(kb + r) * N + base]);
    t[r][c0 + 0] = v.x; t[r][c0 + 1] = v.y; t[r][c0 + 2] = v.z; t[r][c0 + 3] = v.w;
    __syncthreads();
    const int rr  = threadIdx.x >> 3;         // output row within block
    const int cc0 = (threadIdx.x & 7) << 2;   // k offset
    const int ctile = (rr >> 1) + (rr & 1) * 16;
    f16x4_t o;
    o.x = (f16_t)t[cc0 + 0][ctile];
    o.y = (f16_t)t[cc0 + 1][ctile];
    o.z = (f16_t)t[cc0 + 2][ctile];
    o.w = (f16_t)t[cc0 + 3][ctile];
    *reinterpret_cast<f16x4_t*>(&WT[(size_t)(nb + rr) * K + kb + cc0]) = o;
}

// ---------------------------------------------------------------------------
// fp16 MFMA GEMM (m97 pattern): C[M,N] = A[M,K] @ BT[N,K]^T
// 128x128 tile, BK=32, 256 threads = 4 waves, each wave 64x64 (4x4 MFMA tiles).
// MODE 0: C(f32)  = A@B                               (final GEMM)
// MODE 2: C(f16)  = f16(C * (A@B))                    (kv = k*v)
// MODE 4: a-polar fused: val -> val*sigmoid(|a|)/|a|  (f32, interleaved re/im)
// MODE 5: multi-dest f16: N=3072 -> q (Cv), k (Cv2), g (Cv3) by bn>>10
// ---------------------------------------------------------------------------
template <int MODE>
__global__ __launch_bounds__(256, 2) void mfma_gemm_kernel(
    const f16_t* __restrict__ A, const f16_t* __restrict__ BT,
    void* __restrict__ Cv, void* __restrict__ Cv2, void* __restrict__ Cv3,
    int M, int N, int K)
{
    __shared__ __align__(16) f16_t As[128 * 32];   // [m][k], 64B rows
    __shared__ __align__(16) f16_t Bs[128 * 32];   // [n][k]

    const int tid  = threadIdx.x;
    const int wave = tid >> 6;
    const int lane = tid & 63;
    const int bm = blockIdx.y * 128;
    const int bn = blockIdx.x * 128;
    const int wm = (wave & 1) * 64;
    const int wn = (wave >> 1) * 64;

    const int sr = tid >> 2;
    const int sc = (tid & 3) * 8;
    const f16_t* Ag = A  + (size_t)(bm + sr) * K + sc;
    const f16_t* Bg = BT + (size_t)(bn + sr) * K + sc;
    f16_t* Al0 = As + tid * 8;
    f16_t* Al1 = As + 64 * 32 + tid * 8;
    f16_t* Bl0 = Bs + tid * 8;
    f16_t* Bl1 = Bs + 64 * 32 + tid * 8;
    const size_t rowskip = (size_t)64 * K;

    f32x4_t acc[4][4] = {};

    const int fm = lane & 15;
    const int kh = (lane >> 4) << 3;

    for (int kt = 0; kt < K; kt += 32) {
        gload16(Ag + kt, Al0);
        gload16(Ag + rowskip + kt, Al1);
        gload16(Bg + kt, Bl0);
        gload16(Bg + rowskip + kt, Bl1);
        __syncthreads();

        f16x8_t af[4], bfr[4];
        #pragma unroll
        for (int i = 0; i < 4; ++i)
            af[i] = *reinterpret_cast<const f16x8_t*>(&As[(wm + i * 16 + fm) * 32 + kh]);
        #pragma unroll
        for (int j = 0; j < 4; ++j)
            bfr[j] = *reinterpret_cast<const f16x8_t*>(&Bs[(wn + j * 16 + fm) * 32 + kh]);
        #pragma unroll
        for (int i = 0; i < 4; ++i)
            #pragma unroll
            for (int j = 0; j < 4; ++j)
                acc[i][j] = __builtin_amdgcn_mfma_f32_16x16x32_f16(
                    af[i], bfr[j], acc[i][j], 0, 0, 0);
        __syncthreads();
    }

    // epilogue: D row=(lane>>4)*4+reg, col=lane&15  (m89/m91-verified)
    const int erow = (lane >> 4) << 2;
    const int ecol = lane & 15;
    #pragma unroll
    for (int i = 0; i < 4; ++i) {
        #pragma unroll
        for (int j = 0; j < 4; ++j) {
            const int row0 = bm + wm + i * 16 + erow;
            const int col  = bn + wn + j * 16 + ecol;
            #pragma unroll
            for (int rg = 0; rg < 4; ++rg) {
                const size_t idx = (size_t)(row0 + rg) * N + col;
                const float val = acc[i][j][rg];
                if (MODE == 0) {
                    ((float*)Cv)[idx] = val;
                } else if (MODE == 2) {
                    f16_t* C = (f16_t*)Cv;
                    C[idx] = (f16_t)((float)C[idx] * val);
                } else if (MODE == 4) {
                    // adjacent lanes hold (re,im) of one channel
                    const float par = __shfl_xor(val, 1, 64);
                    const float re = (lane & 1) ? par : val;
                    const float im = (lane & 1) ? val : par;
                    const float r = sqrtf(re * re + im * im);
                    float outv;
                    if (r > 0.0f) {
                        const float sg = 1.0f / (1.0f + expf(-r));
                        outv = val * (sg / r);
                    } else {
                        outv = (lane & 1) ? 0.0f : 0.5f;
                    }
                    ((float*)Cv)[idx] = outv;
                } else {  // MODE 5
                    f16_t* dst = (bn < 1024) ? (f16_t*)Cv
                               : (bn < 2048) ? (f16_t*)Cv2 : (f16_t*)Cv3;
                    const size_t didx = (size_t)(row0 + rg) * DDIM + ((bn & 1023) + wn + j * 16 + ecol);
                    dst[didx] = (f16_t)val;
                }
            }
        }
    }
}

// ---------------------------------------------------------------------------
// Scan phase 1: per-(b,chunk,d) local scan; emit (A_prod, H_local) float4.
// a layout: [m][2d]=re, [m][2d+1]=im (interleaved, float2 loads).
// ---------------------------------------------------------------------------
__global__ __launch_bounds__(256) void scan1_kernel(
    const float* __restrict__ a, const f16_t* __restrict__ kvb,
    float4* __restrict__ state)
{
    const int t = blockIdx.x * 256 + threadIdx.x;   // B*NCHUNK*D
    const int d = t & 1023;
    const int c = (t >> 10) & (NCHUNK - 1);
    const int b = t >> 16;
    size_t base  = ((size_t)(b * SDIM + c * LCHUNK)) * DDIM + d;
    const float2* a2 = (const float2*)a;
    float Ar = 1.0f, Ai = 0.0f, Hr = 0.0f, Hi = 0.0f;
    for (int s = 0; s < LCHUNK; ++s) {
        const float2 av = a2[base];
        const float kv = (float)kvb[base];
        const float hr = av.x * Hr - av.y * Hi + kv;
        const float hi = av.x * Hi + av.y * Hr;
        Hr = hr; Hi = hi;
        const float nr = av.x * Ar - av.y * Ai;
        const float ni = av.x * Ai + av.y * Ar;
        Ar = nr; Ai = ni;
        base += DDIM;
    }
    state[t] = make_float4(Ar, Ai, Hr, Hi);
}

// ---------------------------------------------------------------------------
// Scan phase 2: sequential chunk-state combine per channel -> carry-in.
// ---------------------------------------------------------------------------
__global__ __launch_bounds__(256) void scan2_kernel(
    const float4* __restrict__ state, float2* __restrict__ carry)
{
    const int t = blockIdx.x * 256 + threadIdx.x;  // B*D = 4096
    const int d = t & 1023;
    const int b = t >> 10;
    float cr = 0.0f, ci = 0.0f;
    for (int c = 0; c < NCHUNK; ++c) {
        const size_t idx = ((size_t)(b * NCHUNK + c)) * DDIM + d;
        carry[idx] = make_float2(cr, ci);
        const float4 st = state[idx];
        const float nr = st.x * cr - st.y * ci + st.z;
        const float ni = st.x * ci + st.y * cr + st.w;
        cr = nr; ci = ni;
    }
}

// ---------------------------------------------------------------------------
// Scan phase 3: re-scan with carry; y(f16) = q * silu(g) * Re(h),
// written IN-PLACE over kv (same-thread element-wise, safe).
// ---------------------------------------------------------------------------
__global__ __launch_bounds__(256) void scan3_kernel(
    const float* __restrict__ a, f16_t* __restrict__ kvb,
    const f16_t* __restrict__ qb, const f16_t* __restrict__ gb,
    const float2* __restrict__ carry)
{
    const int t = blockIdx.x * 256 + threadIdx.x;   // B*NCHUNK*D
    const int d = t & 1023;
    const int c = (t >> 10) & (NCHUNK - 1);
    const int b = t >> 16;
    size_t base  = ((size_t)(b * SDIM + c * LCHUNK)) * DDIM + d;
    const float2* a2 = (const float2*)a;
    const float2 h0 = carry[t];
    float Hr = h0.x, Hi = h0.y;
    for (int s = 0; s < LCHUNK; ++s) {
        const float2 av = a2[base];
        const float kv = (float)kvb[base];
        const float hr = av.x * Hr - av.y * Hi + kv;
        const float hi = av.x * Hi + av.y * Hr;
        Hr = hr; Hi = hi;
        const float qv = (float)qb[base];
        const float gv = (float)gb[base];
        const float silu = gv / (1.0f + expf(-gv));
        kvb[base] = (f16_t)(qv * silu * Hr);
        base += DDIM;
    }
}

// ---------------------------------------------------------------------------
// kernel_launch
//
// Workspace layout (215 MB total):
//   xn:  [SZ f16]  33.5MB — A operand; scan `state` (4MB) overlaps after death
//   kv:  [SZ f16]  33.5MB — k, then kv=k*v, then y (in-place in scan3)
//   a:   [2*SZ f32] 134MB — interleaved (re,im) channel pairs
//   WT:  [7*WSZ f16] 14MB — q,k,g,v (2MB each), a (4MB), o (2MB);
//        `carry` (2MB) overlaps WTq after the projection GEMMs are done
// q,g (f16) live in the two halves of d_out until the final GEMM overwrites it.
// ---------------------------------------------------------------------------
extern "C" void kernel_launch(void* const* d_in, const int* in_sizes, int n_in,
                              void* d_out, int out_size, void* d_ws, size_t ws_size,
                              hipStream_t stream)
{
    const float* x        = (const float*)d_in[0];
    const float* wq       = (const float*)d_in[1];
    const float* wk       = (const float*)d_in[2];
    const float* wv       = (const float*)d_in[3];
    const float* wa       = (const float*)d_in[4];
    const float* wg       = (const float*)d_in[5];
    const float* wo       = (const float*)d_in[6];
    const float* rms_scale= (const float*)d_in[7];
    float* out = (float*)d_out;

    const size_t SZ = (size_t)MROWS * DDIM;   // 16,777,216 elements
    const size_t WSZ = (size_t)DDIM * DDIM;   // 1,048,576
    char* ws = (char*)d_ws;
    f16_t* xn   = (f16_t*)ws;                          // SZ f16
    f16_t* kv   = (f16_t*)(ws + SZ * 2);               // SZ f16
    float* abuf = (float*)(ws + SZ * 4);               // 2*SZ f32 (interleaved)
    f16_t* WT   = (f16_t*)(ws + SZ * 12);              // 7*WSZ f16
    f16_t* WTq = WT;                 // rows 0..1023 of fused QKG B
    f16_t* WTk = WT + WSZ;           // rows 1024..2047
    f16_t* WTg = WT + 2 * WSZ;       // rows 2048..3071
    f16_t* WTv = WT + 3 * WSZ;
    f16_t* WTa = WT + 4 * WSZ;       // 2M elements (interleaved rows)
    f16_t* WTo = WT + 6 * WSZ;
    float4* state = (float4*)xn;     // overlaps dead xn (4MB)
    float2* carry = (float2*)WT;     // overlaps dead WTq/WTk (2MB)

    f16_t* qb = (f16_t*)d_out;       // q f16 in first half of d_out
    f16_t* gb = qb + SZ;             // g f16 in second half

    const size_t needed = SZ * 12 + 7 * WSZ * 2;
    if (ws_size < needed) {
        const float marker = (float)(ws_size >> 20);
        fill_kernel<<<(out_size + 255) / 256, 256, 0, stream>>>(out, out_size, marker);
        return;
    }

    // 1. RMSNorm -> f16 xn
    rmsnorm_kernel<<<MROWS, 256, 0, stream>>>(x, rms_scale, xn);

    // 2. Weight prep
    dim3 tblk(256);
    dim3 tg1(DDIM / 32, DDIM / 32);
    transpose_f16_kernel<<<tg1, tblk, 0, stream>>>(wq, WTq, DDIM, DDIM);
    transpose_f16_kernel<<<tg1, tblk, 0, stream>>>(wk, WTk, DDIM, DDIM);
    transpose_f16_kernel<<<tg1, tblk, 0, stream>>>(wg, WTg, DDIM, DDIM);
    transpose_f16_kernel<<<tg1, tblk, 0, stream>>>(wv, WTv, DDIM, DDIM);
    transpose_f16_kernel<<<tg1, tblk, 0, stream>>>(wo, WTo, DDIM, DDIM);
    dim3 tga(2 * DDIM / 32, DDIM / 32);
    transpose_a_kernel<<<tga, tblk, 0, stream>>>(wa, WTa);

    // 3. Projections
    dim3 blk(256);
    dim3 gqkg(3 * DDIM / 128, MROWS / 128);   // (24,128) fused q,k,g
    dim3 g1(DDIM / 128, MROWS / 128);         // (8,128)
    dim3 g2(2 * DDIM / 128, MROWS / 128);     // (16,128)
    mfma_gemm_kernel<5><<<gqkg, blk, 0, stream>>>(xn, WT,  qb, kv, gb, MROWS, 3 * DDIM, DDIM);
    mfma_gemm_kernel<2><<<g1,   blk, 0, stream>>>(xn, WTv, kv, nullptr, nullptr, MROWS, DDIM, DDIM);   // kv = k*v
    mfma_gemm_kernel<4><<<g2,   blk, 0, stream>>>(xn, WTa, abuf, nullptr, nullptr, MROWS, 2 * DDIM, DDIM); // a (polar fused)

    // 4. chunked complex scan
    const int nscan = BDIM * NCHUNK * DDIM;   // 262144
    scan1_kernel<<<nscan / 256, 256, 0, stream>>>(abuf, kv, state);
    scan2_kernel<<<(BDIM * DDIM) / 256, 256, 0, stream>>>(state, carry);
    scan3_kernel<<<nscan / 256, 256, 0, stream>>>(abuf, kv, qb, gb, carry);

    // 5. out = y @ wo   (y lives in kv buffer)
    mfma_gemm_kernel<0><<<g1, blk, 0, stream>>>(kv, WTo, out, nullptr, nullptr, MROWS, DDIM, DDIM);
}

// Round 7
// 551.966 us; speedup vs baseline: 5.9850x; 1.0712x over previous
//
#include <hip/hip_runtime.h>
#include <hip/hip_bf16.h>
#include <math.h>

// Problem constants (B,S,D) = (4,4096,1024)
#define BDIM 4
#define SDIM 4096
#define DDIM 1024
#define MROWS (BDIM*SDIM)      // 16384
#define EPS 1e-6f
#define NCHUNK 64              // chunks along S
#define LCHUNK 64              // chunk length (NCHUNK*LCHUNK == SDIM)

typedef _Float16 f16_t;
typedef _Float16 f16x2_t __attribute__((ext_vector_type(2)));
typedef _Float16 f16x4_t __attribute__((ext_vector_type(4)));
typedef _Float16 f16x8_t __attribute__((ext_vector_type(8)));     // MFMA A/B frag (4 VGPRs)
typedef float    f32x4_t __attribute__((ext_vector_type(4)));     // MFMA C/D frag

// async global->LDS, 16B per lane (dest = wave-uniform base + lane*16)
__device__ __forceinline__ void gload16(const void* g, void* l) {
    __builtin_amdgcn_global_load_lds(
        (const __attribute__((address_space(1))) unsigned int*)g,
        (__attribute__((address_space(3))) unsigned int*)l, 16, 0, 0);
}

// ---------------------------------------------------------------------------
// Guard-fail fill (encodes ws_size MB as output on too-small workspace)
// ---------------------------------------------------------------------------
__global__ __launch_bounds__(256) void fill_kernel(float* __restrict__ out,
                                                   int n, float val)
{
    const int i = blockIdx.x * 256 + threadIdx.x;
    if (i < n) out[i] = val;
}

// ---------------------------------------------------------------------------
// RMSNorm: one block per row of D=1024; outputs fp16 xn.
// ---------------------------------------------------------------------------
__global__ __launch_bounds__(256) void rmsnorm_kernel(
    const float* __restrict__ x, const float* __restrict__ scale,
    f16_t* __restrict__ xn)
{
    const int row = blockIdx.x;
    const int tid = threadIdx.x;
    const float4 v = reinterpret_cast<const float4*>(x + (size_t)row * DDIM)[tid];
    float ss = v.x*v.x + v.y*v.y + v.z*v.z + v.w*v.w;
    #pragma unroll
    for (int off = 32; off > 0; off >>= 1)
        ss += __shfl_down(ss, off, 64);
    __shared__ float red[4];
    if ((tid & 63) == 0) red[tid >> 6] = ss;
    __syncthreads();
    ss = red[0] + red[1] + red[2] + red[3];
    const float inv = rsqrtf(ss * (1.0f / DDIM) + EPS);
    const float4 sc = reinterpret_cast<const float4*>(scale)[tid];
    f16x4_t o;
    o.x = (f16_t)(v.x * inv * sc.x);
    o.y = (f16_t)(v.y * inv * sc.y);
    o.z = (f16_t)(v.z * inv * sc.z);
    o.w = (f16_t)(v.w * inv * sc.w);
    reinterpret_cast<f16x4_t*>(xn + (size_t)row * DDIM)[tid] = o;
}

// ---------------------------------------------------------------------------
// Weight prep (merged): 5 square weights W[K][N] f32 -> WT[N][K] f16.
// blockIdx.z selects the weight; destination offsets {0,1,2,3,6}*WSZ
// (wo goes to slot 6; slots 4..5 belong to WTa).
// ---------------------------------------------------------------------------
__global__ __launch_bounds__(256) void transpose5_kernel(
    const float* __restrict__ w0, const float* __restrict__ w1,
    const float* __restrict__ w2, const float* __restrict__ w3,
    const float* __restrict__ w4, f16_t* __restrict__ WT)
{
    const int K = DDIM, N = DDIM;
    const int z = blockIdx.z;
    const float* W = (z == 0) ? w0 : (z == 1) ? w1 : (z == 2) ? w2
                   : (z == 3) ? w3 : w4;
    const int zoff = (z == 4) ? 6 : z;   // wo -> slot 6 (WTa occupies 4..5)
    f16_t* dst = WT + (size_t)zoff * DDIM * DDIM;
    __shared__ float t[32][33];
    const int kb = blockIdx.y * 32;
    const int nb = blockIdx.x * 32;
    const int r  = threadIdx.x >> 3;
    const int c0 = (threadIdx.x & 7) << 2;
    const float4 v = *reinterpret_cast<const float4*>(&W[(size_t)(kb + r) * N + nb + c0]);
    t[r][c0 + 0] = v.x; t[r][c0 + 1] = v.y; t[r][c0 + 2] = v.z; t[r][c0 + 3] = v.w;
    __syncthreads();
    f16x4_t o;
    o.x = (f16_t)t[c0 + 0][r];
    o.y = (f16_t)t[c0 + 1][r];
    o.z = (f16_t)t[c0 + 2][r];
    o.w = (f16_t)t[c0 + 3][r];
    *reinterpret_cast<f16x4_t*>(&dst[(size_t)(nb + r) * K + kb + c0]) = o;
}

// ---------------------------------------------------------------------------
// Weight prep for wa: W[K][2048] f32 -> WTa[n][K] f16 with INTERLEAVED rows:
// output row n corresponds to original column (n>>1) + (n&1)*1024.
// ---------------------------------------------------------------------------
__global__ __launch_bounds__(256) void transpose_a_kernel(
    const float* __restrict__ W, f16_t* __restrict__ WT)
{
    const int K = DDIM, N = 2 * DDIM;
    __shared__ float t[32][33];
    const int kb = blockIdx.y * 32;
    const int nb = blockIdx.x * 32;
    const int r  = threadIdx.x >> 3;
    const int c0 = (threadIdx.x & 7) << 2;
    const int base = (c0 < 16) ? ((nb >> 1) + c0) : (DDIM + (nb >> 1) + c0 - 16);
    const float4 v = *reinterpret_cast<const float4*>(&W[(size_t)(kb + r) * N + base]);
    t[r][c0 + 0] = v.x; t[r][c0 + 1] = v.y; t[r][c0 + 2] = v.z; t[r][c0 + 3] = v.w;
    __syncthreads();
    const int rr  = threadIdx.x >> 3;
    const int cc0 = (threadIdx.x & 7) << 2;
    const int ctile = (rr >> 1) + (rr & 1) * 16;
    f16x4_t o;
    o.x = (f16_t)t[cc0 + 0][ctile];
    o.y = (f16_t)t[cc0 + 1][ctile];
    o.z = (f16_t)t[cc0 + 2][ctile];
    o.w = (f16_t)t[cc0 + 3][ctile];
    *reinterpret_cast<f16x4_t*>(&WT[(size_t)(nb + rr) * K + kb + cc0]) = o;
}

// ---------------------------------------------------------------------------
// fp16 MFMA GEMM (m97 pattern): C[M,N] = A[M,K] @ BT[N,K]^T
// 128x128 tile, BK=32, 256 threads = 4 waves, each wave 64x64 (4x4 MFMA tiles).
// MODE 0: C(f32)  = A@B                               (final GEMM)
// MODE 2: C(f16)  = f16(C * (A@B))                    (kv = k*v)
// MODE 4: a-polar fused -> f16: val*sigmoid(|a|)/|a|  (interleaved re/im)
// MODE 5: multi-dest f16: N=3072 -> q (Cv), k (Cv2), g (Cv3) by bn
// ---------------------------------------------------------------------------
template <int MODE>
__global__ __launch_bounds__(256, 2) void mfma_gemm_kernel(
    const f16_t* __restrict__ A, const f16_t* __restrict__ BT,
    void* __restrict__ Cv, void* __restrict__ Cv2, void* __restrict__ Cv3,
    int M, int N, int K)
{
    __shared__ __align__(16) f16_t As[128 * 32];   // [m][k], 64B rows
    __shared__ __align__(16) f16_t Bs[128 * 32];   // [n][k]

    const int tid  = threadIdx.x;
    const int wave = tid >> 6;
    const int lane = tid & 63;
    const int bm = blockIdx.y * 128;
    const int bn = blockIdx.x * 128;
    const int wm = (wave & 1) * 64;
    const int wn = (wave >> 1) * 64;

    const int sr = tid >> 2;
    const int sc = (tid & 3) * 8;
    const f16_t* Ag = A  + (size_t)(bm + sr) * K + sc;
    const f16_t* Bg = BT + (size_t)(bn + sr) * K + sc;
    f16_t* Al0 = As + tid * 8;
    f16_t* Al1 = As + 64 * 32 + tid * 8;
    f16_t* Bl0 = Bs + tid * 8;
    f16_t* Bl1 = Bs + 64 * 32 + tid * 8;
    const size_t rowskip = (size_t)64 * K;

    f32x4_t acc[4][4] = {};

    const int fm = lane & 15;
    const int kh = (lane >> 4) << 3;

    for (int kt = 0; kt < K; kt += 32) {
        gload16(Ag + kt, Al0);
        gload16(Ag + rowskip + kt, Al1);
        gload16(Bg + kt, Bl0);
        gload16(Bg + rowskip + kt, Bl1);
        __syncthreads();

        f16x8_t af[4], bfr[4];
        #pragma unroll
        for (int i = 0; i < 4; ++i)
            af[i] = *reinterpret_cast<const f16x8_t*>(&As[(wm + i * 16 + fm) * 32 + kh]);
        #pragma unroll
        for (int j = 0; j < 4; ++j)
            bfr[j] = *reinterpret_cast<const f16x8_t*>(&Bs[(wn + j * 16 + fm) * 32 + kh]);
        #pragma unroll
        for (int i = 0; i < 4; ++i)
            #pragma unroll
            for (int j = 0; j < 4; ++j)
                acc[i][j] = __builtin_amdgcn_mfma_f32_16x16x32_f16(
                    af[i], bfr[j], acc[i][j], 0, 0, 0);
        __syncthreads();
    }

    // epilogue: D row=(lane>>4)*4+reg, col=lane&15  (m89/m91-verified)
    const int erow = (lane >> 4) << 2;
    const int ecol = lane & 15;
    #pragma unroll
    for (int i = 0; i < 4; ++i) {
        #pragma unroll
        for (int j = 0; j < 4; ++j) {
            const int row0 = bm + wm + i * 16 + erow;
            const int col  = bn + wn + j * 16 + ecol;
            #pragma unroll
            for (int rg = 0; rg < 4; ++rg) {
                const size_t idx = (size_t)(row0 + rg) * N + col;
                const float val = acc[i][j][rg];
                if (MODE == 0) {
                    ((float*)Cv)[idx] = val;
                } else if (MODE == 2) {
                    f16_t* C = (f16_t*)Cv;
                    C[idx] = (f16_t)((float)C[idx] * val);
                } else if (MODE == 4) {
                    // adjacent lanes hold (re,im) of one channel
                    const float par = __shfl_xor(val, 1, 64);
                    const float re = (lane & 1) ? par : val;
                    const float im = (lane & 1) ? val : par;
                    const float r = sqrtf(re * re + im * im);
                    float outv;
                    if (r > 0.0f) {
                        const float sg = 1.0f / (1.0f + __expf(-r));
                        outv = val * (sg / r);
                    } else {
                        outv = (lane & 1) ? 0.0f : 0.5f;
                    }
                    ((f16_t*)Cv)[idx] = (f16_t)outv;
                } else {  // MODE 5
                    f16_t* dst = (bn < 1024) ? (f16_t*)Cv
                               : (bn < 2048) ? (f16_t*)Cv2 : (f16_t*)Cv3;
                    const size_t didx = (size_t)(row0 + rg) * DDIM + ((bn & 1023) + wn + j * 16 + ecol);
                    dst[didx] = (f16_t)val;
                }
            }
        }
    }
}

// ---------------------------------------------------------------------------
// Scan phase 1: per-(b,chunk,d) local scan; emit (A_prod, H_local) float4.
// a layout: [m][d] = f16x2 (re,im).
// ---------------------------------------------------------------------------
__global__ __launch_bounds__(256) void scan1_kernel(
    const f16x2_t* __restrict__ a2, const f16_t* __restrict__ kvb,
    float4* __restrict__ state)
{
    const int t = blockIdx.x * 256 + threadIdx.x;   // B*NCHUNK*D
    const int d = t & 1023;
    const int c = (t >> 10) & (NCHUNK - 1);
    const int b = t >> 16;
    size_t base  = ((size_t)(b * SDIM + c * LCHUNK)) * DDIM + d;
    float Ar = 1.0f, Ai = 0.0f, Hr = 0.0f, Hi = 0.0f;
    for (int s = 0; s < LCHUNK; ++s) {
        const f16x2_t av = a2[base];
        const float arr = (float)av.x;
        const float aii = (float)av.y;
        const float kv = (float)kvb[base];
        const float hr = arr * Hr - aii * Hi + kv;
        const float hi = arr * Hi + aii * Hr;
        Hr = hr; Hi = hi;
        const float nr = arr * Ar - aii * Ai;
        const float ni = arr * Ai + aii * Ar;
        Ar = nr; Ai = ni;
        base += DDIM;
    }
    state[t] = make_float4(Ar, Ai, Hr, Hi);
}

// ---------------------------------------------------------------------------
// Scan phase 2: wave-parallel chunk combine. Lane c holds chunk c's state;
// 6-step Hillis-Steele inclusive scan of (A,H)∘, then exclusive-shift -> carry.
// ---------------------------------------------------------------------------
__global__ __launch_bounds__(256) void scan2_kernel(
    const float4* __restrict__ state, float2* __restrict__ carry)
{
    const int t = blockIdx.x * 256 + threadIdx.x;   // B*D*64 threads
    const int c = t & 63;            // chunk index = lane
    const int ch = t >> 6;           // channel: b*1024+d
    const int d = ch & 1023;
    const int b = ch >> 10;
    const size_t idx = ((size_t)(b * NCHUNK + c)) * DDIM + d;
    const float4 st = state[idx];
    float Ar = st.x, Ai = st.y, Hr = st.z, Hi = st.w;
    #pragma unroll
    for (int off = 1; off < 64; off <<= 1) {
        const float pAr = __shfl_up(Ar, off, 64);
        const float pAi = __shfl_up(Ai, off, 64);
        const float pHr = __shfl_up(Hr, off, 64);
        const float pHi = __shfl_up(Hi, off, 64);
        if (c >= off) {
            // compose(earlier=(pA,pH), current=(A,H)): A·pA, A·pH + H
            const float nHr = Ar * pHr - Ai * pHi + Hr;
            const float nHi = Ar * pHi + Ai * pHr + Hi;
            const float nAr = Ar * pAr - Ai * pAi;
            const float nAi = Ar * pAi + Ai * pAr;
            Ar = nAr; Ai = nAi; Hr = nHr; Hi = nHi;
        }
    }
    // exclusive prefix: carry into chunk c = inclusive H at chunk c-1
    const float eHr = __shfl_up(Hr, 1, 64);
    const float eHi = __shfl_up(Hi, 1, 64);
    carry[idx] = make_float2(c == 0 ? 0.0f : eHr, c == 0 ? 0.0f : eHi);
}

// ---------------------------------------------------------------------------
// Scan phase 3: re-scan with carry; y(f16) = q * silu(g) * Re(h),
// written IN-PLACE over kv.
// ---------------------------------------------------------------------------
__global__ __launch_bounds__(256) void scan3_kernel(
    const f16x2_t* __restrict__ a2, f16_t* __restrict__ kvb,
    const f16_t* __restrict__ qb, const f16_t* __restrict__ gb,
    const float2* __restrict__ carry)
{
    const int t = blockIdx.x * 256 + threadIdx.x;   // B*NCHUNK*D
    const int d = t & 1023;
    const int c = (t >> 10) & (NCHUNK - 1);
    const int b = t >> 16;
    size_t base  = ((size_t)(b * SDIM + c * LCHUNK)) * DDIM + d;
    const float2 h0 = carry[t];
    float Hr = h0.x, Hi = h0.y;
    for (int s = 0; s < LCHUNK; ++s) {
        const f16x2_t av = a2[base];
        const float arr = (float)av.x;
        const float aii = (float)av.y;
        const float kv = (float)kvb[base];
        const float hr = arr * Hr - aii * Hi + kv;
        const float hi = arr * Hi + aii * Hr;
        Hr = hr; Hi = hi;
        const float qv = (float)qb[base];
        const float gv = (float)gb[base];
        const float silu = gv / (1.0f + __expf(-gv));
        kvb[base] = (f16_t)(qv * silu * Hr);
        base += DDIM;
    }
}

// ---------------------------------------------------------------------------
// kernel_launch
//
// Workspace layout (149 MB):
//   xn:  [SZ f16]   33.5MB — A operand; scan `state` (4MB) overlaps after death
//   kv:  [SZ f16]   33.5MB — k, then kv=k*v, then y (in-place in scan3)
//   a:   [SZ f16x2] 67MB   — interleaved (re,im) channel pairs
//   WT:  [7*WSZ f16] 14MB  — slots: 0=q 1=k 2=g 3=v 4..5=a(interleaved) 6=o;
//        `carry` (2MB) overlaps dead WTq after the projection GEMMs
// q,g (f16) live in the two halves of d_out until the final GEMM overwrites it.
// ---------------------------------------------------------------------------
extern "C" void kernel_launch(void* const* d_in, const int* in_sizes, int n_in,
                              void* d_out, int out_size, void* d_ws, size_t ws_size,
                              hipStream_t stream)
{
    const float* x        = (const float*)d_in[0];
    const float* wq       = (const float*)d_in[1];
    const float* wk       = (const float*)d_in[2];
    const float* wv       = (const float*)d_in[3];
    const float* wa       = (const float*)d_in[4];
    const float* wg       = (const float*)d_in[5];
    const float* wo       = (const float*)d_in[6];
    const float* rms_scale= (const float*)d_in[7];
    float* out = (float*)d_out;

    const size_t SZ = (size_t)MROWS * DDIM;   // 16,777,216 elements
    const size_t WSZ = (size_t)DDIM * DDIM;   // 1,048,576
    char* ws = (char*)d_ws;
    f16_t*   xn   = (f16_t*)ws;                        // SZ f16
    f16_t*   kv   = (f16_t*)(ws + SZ * 2);             // SZ f16
    f16x2_t* abuf = (f16x2_t*)(ws + SZ * 4);           // SZ f16x2
    f16_t*   WT   = (f16_t*)(ws + SZ * 8);             // 7*WSZ f16
    f16_t* WTv = WT + 3 * WSZ;
    f16_t* WTa = WT + 4 * WSZ;       // 2M elements (interleaved rows), slots 4..5
    f16_t* WTo = WT + 6 * WSZ;       // slot 6
    float4* state = (float4*)xn;     // overlaps dead xn (4MB)
    float2* carry = (float2*)WT;     // overlaps dead WTq (2MB)

    f16_t* qb = (f16_t*)d_out;       // q f16 in first half of d_out
    f16_t* gb = qb + SZ;             // g f16 in second half

    const size_t needed = SZ * 8 + 7 * WSZ * 2;
    if (ws_size < needed) {
        const float marker = (float)(ws_size >> 20);
        fill_kernel<<<(out_size + 255) / 256, 256, 0, stream>>>(out, out_size, marker);
        return;
    }

    // 1. RMSNorm -> f16 xn
    rmsnorm_kernel<<<MROWS, 256, 0, stream>>>(x, rms_scale, xn);

    // 2. Weight prep (2 launches)
    dim3 tblk(256);
    dim3 tg5(DDIM / 32, DDIM / 32, 5);
    transpose5_kernel<<<tg5, tblk, 0, stream>>>(wq, wk, wg, wv, wo, WT);
    dim3 tga(2 * DDIM / 32, DDIM / 32);
    transpose_a_kernel<<<tga, tblk, 0, stream>>>(wa, WTa);

    // 3. Projections
    dim3 blk(256);
    dim3 gqkg(3 * DDIM / 128, MROWS / 128);   // (24,128) fused q,k,g
    dim3 g1(DDIM / 128, MROWS / 128);         // (8,128)
    dim3 g2(2 * DDIM / 128, MROWS / 128);     // (16,128)
    mfma_gemm_kernel<5><<<gqkg, blk, 0, stream>>>(xn, WT,  qb, kv, gb, MROWS, 3 * DDIM, DDIM);
    mfma_gemm_kernel<2><<<g1,   blk, 0, stream>>>(xn, WTv, kv, nullptr, nullptr, MROWS, DDIM, DDIM);   // kv = k*v
    mfma_gemm_kernel<4><<<g2,   blk, 0, stream>>>(xn, WTa, abuf, nullptr, nullptr, MROWS, 2 * DDIM, DDIM); // a

    // 4. chunked complex scan
    const int nscan = BDIM * NCHUNK * DDIM;   // 262144
    scan1_kernel<<<nscan / 256, 256, 0, stream>>>(abuf, kv, state);
    scan2_kernel<<<nscan / 256, 256, 0, stream>>>(state, carry);
    scan3_kernel<<<nscan / 256, 256, 0, stream>>>(abuf, kv, qb, gb, carry);

    // 5. out = y @ wo   (y lives in kv buffer)
    mfma_gemm_kernel<0><<<g1, blk, 0, stream>>>(kv, WTo, out, nullptr, nullptr, MROWS, DDIM, DDIM);
}